// Round 1
// baseline (323.127 us; speedup 1.0000x reference)
//
#include <hip/hip_runtime.h>

// ---------------------------------------------------------------------------
// Attention_33638183862624  (linear "Taylor-softmax" attention)
// B=16, C=512, CQK=64, N=4096.  fp32 in/out, bf16 MFMA internally.
//   T[m,k]   = sum_n Kn[m,n] x[k,n]
//   matrix   = T * Wv^T + bv (x) Ksum
//   Vsum[c]  = Wv[c,:]*xsum + N*bv[c]
//   out[c,n] = gamma * tailor[n] * (Vsum[c] + sum_m Qn[m,n]*matrix[m,c])
// R2: k_qk/k_t restructured -> BK=64, register prefetch + LDS double buffer,
//     ONE __syncthreads per K-chunk (pending reg-loads need no vmcnt drain).
// R3: (a) k_t split-K atomics (4.19M device-scope f32 atomicAdds) replaced by
//     non-atomic partial stores Tpart[8][b][64][512] + new k_red reduction
//     kernel (theory: atomic drain at the cross-XCD coherent point was tens
//     of us).  (b) k_mat inner loop: 2m x 4c register blocking with f32x4 LDS
//     reads (4608 ds_read_b32/thread -> 768 ds_read_b128/thread).
// ---------------------------------------------------------------------------

typedef __attribute__((ext_vector_type(8))) short short8_t;
typedef __attribute__((ext_vector_type(4))) float f32x4;

__device__ __forceinline__ unsigned short f2bf(float f) {
  union { float f; unsigned u; } v; v.f = f;
  unsigned r = v.u + 0x7FFFu + ((v.u >> 16) & 1u);   // RNE
  return (unsigned short)(r >> 16);
}
__device__ __forceinline__ float bf2f(unsigned short h) {
  union { unsigned u; float f; } v; v.u = ((unsigned)h) << 16;
  return v.f;
}

#define MFMA(a, b, c) __builtin_amdgcn_mfma_f32_16x16x32_bf16((a), (b), (c), 0, 0, 0)

// ---------------------------------------------------------------------------
// k_prep: pack Wq (rows 0..63) and Wk (rows 64..127) into bf16 [128][512]
// ---------------------------------------------------------------------------
__global__ void k_prep(const float* __restrict__ Wq, const float* __restrict__ Wk,
                       unsigned short* __restrict__ Wqk) {
  int idx = blockIdx.x * 256 + threadIdx.x;       // 65536 total
  int o = idx >> 9, c = idx & 511;
  float v = (o < 64) ? Wq[o * 512 + c] : Wk[(o - 64) * 512 + c];
  Wqk[idx] = f2bf(v);
}

// ---------------------------------------------------------------------------
// k_qk: per batch GEMM  QK[128 o][4096 n] = Wqk[128][512] * x[512][4096]
// tile 128o x 128n, BK=64, dbuf+prefetch.  Fused: bias, col L2 norm,
// QnT[b][n][64] bf16 (transposed), Kn[b][64][n] bf16, Ksum atomics.
// grid (32 ntiles, 16 batches), 256 threads.
// ---------------------------------------------------------------------------
__launch_bounds__(256, 2)
__global__ void k_qk(const float* __restrict__ x, const unsigned short* __restrict__ Wqk,
                     const float* __restrict__ bq, const float* __restrict__ bk,
                     unsigned short* __restrict__ QnT, unsigned short* __restrict__ KnG,
                     float* __restrict__ Ksum) {
  __shared__ __align__(16) unsigned char smem[77312];
  unsigned short* SAb[2] = {(unsigned short*)(smem + 0),
                            (unsigned short*)(smem + 18432)};   // 128 x 72 each
  unsigned short* SBb[2] = {(unsigned short*)(smem + 36864),
                            (unsigned short*)(smem + 55296)};   // 128 x 72 each
  unsigned short* EQ = (unsigned short*)(smem + 0);       // 128 x 72 (epilogue)
  unsigned short* EK = (unsigned short*)(smem + 18432);   // 64 x 136 (epilogue)
  float* ssq   = (float*)(smem + 73728);                  // [4][128]
  float* invq  = (float*)(smem + 75776);                  // [128]
  float* invk  = (float*)(smem + 76288);                  // [128]
  float* biasL = (float*)(smem + 76800);                  // [128]

  const int t = threadIdx.x;
  const int lane = t & 63, w = t >> 6;
  const int l15 = lane & 15, quad = lane >> 4;
  const int nt = blockIdx.x, b = blockIdx.y;
  const int n0 = nt * 128;
  const float* xb = x + (size_t)b * 512 * 4096;

  if (t < 128) biasL[t] = (t < 64) ? bq[t] : bk[t - 64];

  f32x4 acc[2][8];
#pragma unroll
  for (int i = 0; i < 2; ++i)
#pragma unroll
    for (int j = 0; j < 8; ++j) acc[i][j] = (f32x4){0.f, 0.f, 0.f, 0.f};

  const int nB = t & 127;     // column handled by this thread in B-staging
  const int cgB = t >> 7;     // 0/1 (32 c's each)
  const float* bsrc0 = xb + (size_t)(cgB * 32) * 4096 + n0 + nB;

  short8_t apre[4];
  float bpre[32];

#define QK_LOADA(kc_) do {                                                     \
    const int c0_ = (kc_) * 64;                                                \
    _Pragma("unroll")                                                          \
    for (int p = 0; p < 4; ++p) {                                              \
      int gid = t + p * 256; int o_ = gid >> 3, cg = gid & 7;                  \
      apre[p] = *(const short8_t*)(Wqk + o_ * 512 + c0_ + cg * 8);             \
    } } while (0)

#define QK_LOADB(kc_) do {                                                     \
    const float* s_ = bsrc0 + (size_t)(kc_) * 64 * 4096;                       \
    _Pragma("unroll")                                                          \
    for (int i = 0; i < 32; ++i) bpre[i] = s_[(size_t)i * 4096];               \
    } while (0)

#define QK_STORE(pb) do {                                                      \
    unsigned short* SAp = SAb[pb]; unsigned short* SBp = SBb[pb];              \
    _Pragma("unroll")                                                          \
    for (int p = 0; p < 4; ++p) {                                              \
      int gid = t + p * 256; int o_ = gid >> 3, cg = gid & 7;                  \
      *(short8_t*)(SAp + o_ * 72 + cg * 8) = apre[p];                          \
    }                                                                          \
    _Pragma("unroll")                                                          \
    for (int j = 0; j < 4; ++j) {                                              \
      short8_t v_;                                                             \
      _Pragma("unroll")                                                        \
      for (int e = 0; e < 8; ++e) v_[e] = (short)f2bf(bpre[j * 8 + e]);        \
      *(short8_t*)(SBp + nB * 72 + cgB * 32 + j * 8) = v_;                     \
    } } while (0)

#define QK_MM(pb) do {                                                         \
    const unsigned short* SAp = SAb[pb]; const unsigned short* SBp = SBb[pb];  \
    _Pragma("unroll")                                                          \
    for (int s = 0; s < 2; ++s) {                                              \
      short8_t a0 = *(const short8_t*)(SAp + (w * 32 + l15) * 72 + s * 32 + quad * 8);      \
      short8_t a1 = *(const short8_t*)(SAp + (w * 32 + 16 + l15) * 72 + s * 32 + quad * 8); \
      _Pragma("unroll")                                                        \
      for (int tc = 0; tc < 8; ++tc) {                                         \
        short8_t bf_ = *(const short8_t*)(SBp + (tc * 16 + l15) * 72 + s * 32 + quad * 8);  \
        acc[0][tc] = MFMA(a0, bf_, acc[0][tc]);                                \
        acc[1][tc] = MFMA(a1, bf_, acc[1][tc]);                                \
      } } } while (0)

  QK_LOADA(0); QK_LOADB(0);
#pragma unroll
  for (int kc = 0; kc < 8; ++kc) {
    const int pb = kc & 1;
    QK_STORE(pb);
    if (kc < 7) { QK_LOADA(kc + 1); QK_LOADB(kc + 1); }
    __syncthreads();
    QK_MM(pb);
  }
  __syncthreads();

  // add bias (per output channel o)
#pragma unroll
  for (int trl = 0; trl < 2; ++trl)
#pragma unroll
    for (int reg = 0; reg < 4; ++reg) {
      int o = w * 32 + trl * 16 + quad * 4 + reg;
      float bias = biasL[o];
#pragma unroll
      for (int tc = 0; tc < 8; ++tc) acc[trl][tc][reg] += bias;
    }

  // per-column sum of squares: reduce this wave's 32-o slice per column
#pragma unroll
  for (int tc = 0; tc < 8; ++tc) {
    float v = 0.f;
#pragma unroll
    for (int trl = 0; trl < 2; ++trl)
#pragma unroll
      for (int reg = 0; reg < 4; ++reg) {
        float q = acc[trl][tc][reg];
        v += q * q;
      }
    v += __shfl_xor(v, 16);
    v += __shfl_xor(v, 32);
    if (quad == 0) ssq[w * 128 + tc * 16 + l15] = v;
  }
  __syncthreads();
  if (t < 128) {
    float qs = ssq[t] + ssq[128 + t];
    float ks = ssq[256 + t] + ssq[384 + t];
    invq[t] = 1.0f / fmaxf(sqrtf(qs), 1e-6f);
    invk[t] = 1.0f / fmaxf(sqrtf(ks), 1e-6f);
  }
  __syncthreads();

  if (w < 2) {
    // Q waves (o 0..63): write normalized, transposed, into EQ[n][o]
#pragma unroll
    for (int trl = 0; trl < 2; ++trl)
#pragma unroll
      for (int tc = 0; tc < 8; ++tc) {
        int n = tc * 16 + l15;
        float inv = invq[n];
#pragma unroll
        for (int reg = 0; reg < 4; ++reg) {
          int o = w * 32 + trl * 16 + quad * 4 + reg;
          EQ[n * 72 + o] = f2bf(acc[trl][tc][reg] * inv);
        }
      }
  } else {
    // K waves (o 64..127 -> m 0..63): EK[m][n] + Ksum atomics
#pragma unroll
    for (int trl = 0; trl < 2; ++trl)
#pragma unroll
      for (int reg = 0; reg < 4; ++reg) {
        int m = (w - 2) * 32 + trl * 16 + quad * 4 + reg;
        float p = 0.f;
#pragma unroll
        for (int tc = 0; tc < 8; ++tc) {
          int n = tc * 16 + l15;
          float val = acc[trl][tc][reg] * invk[n];
          EK[m * 136 + n] = f2bf(val);
          p += val;
        }
        p += __shfl_xor(p, 1);
        p += __shfl_xor(p, 2);
        p += __shfl_xor(p, 4);
        p += __shfl_xor(p, 8);
        if (l15 == 0) atomicAdd(Ksum + b * 64 + m, p);
      }
  }
  __syncthreads();

  // cooperative coalesced global stores
  unsigned short* qdst = QnT + ((size_t)b * 4096 + n0) * 64;
#pragma unroll
  for (int p = 0; p < 4; ++p) {
    int idx = t + p * 256;
    int row = idx >> 3, seg = idx & 7;
    *(short8_t*)(qdst + row * 64 + seg * 8) = *(const short8_t*)(EQ + row * 72 + seg * 8);
  }
  unsigned short* kdst = KnG + (size_t)b * 64 * 4096 + n0;
#pragma unroll
  for (int p = 0; p < 4; ++p) {
    int idx = t + p * 256;
    int row = idx >> 4, seg = idx & 15;
    *(short8_t*)(kdst + (size_t)row * 4096 + seg * 8) =
        *(const short8_t*)(EK + row * 136 + seg * 8);
  }
#undef QK_LOADA
#undef QK_LOADB
#undef QK_STORE
#undef QK_MM
}

// ---------------------------------------------------------------------------
// k_t:  Tpart[ns][b][64 m][512 k] = sum_{n in split ns} Kn[m,n]*x[k,n]
// Non-atomic partial stores (R3); xsum[b][k] still via (tiny) atomics.
// BK=64 chunks, dbuf+prefetch.
// grid (8 nsplits, 4 ctiles, 16 batches), 256 threads.
// ---------------------------------------------------------------------------
__launch_bounds__(256, 2)
__global__ void k_t(const float* __restrict__ x, const unsigned short* __restrict__ KnG,
                    float* __restrict__ Tpart, float* __restrict__ xsum) {
  __shared__ __align__(16) unsigned char smem[55296];
  unsigned short* SAb[2] = {(unsigned short*)(smem + 0),
                            (unsigned short*)(smem + 9216)};    // 64 x 72 each
  unsigned short* SBb[2] = {(unsigned short*)(smem + 18432),
                            (unsigned short*)(smem + 36864)};   // 128 x 72 each
  const int t = threadIdx.x;
  const int lane = t & 63, w = t >> 6;
  const int l15 = lane & 15, quad = lane >> 4;
  const int ns = blockIdx.x, ct = blockIdx.y, b = blockIdx.z;
  const int c0 = ct * 128;
  const float* xb = x + (size_t)b * 512 * 4096;
  const unsigned short* Knb = KnG + (size_t)b * 64 * 4096 + ns * 512;

  f32x4 acc[4][2];
#pragma unroll
  for (int i = 0; i < 4; ++i)
#pragma unroll
    for (int j = 0; j < 2; ++j) acc[i][j] = (f32x4){0.f, 0.f, 0.f, 0.f};

  const int row = t >> 1, half = t & 1;
  float xs = 0.f;
  const float* bbase = xb + (size_t)(c0 + row) * 4096 + ns * 512 + half * 32;

  short8_t apre[2];
  f32x4 bpre[8];

#define T_LOADA(ch_) do {                                                      \
    _Pragma("unroll")                                                          \
    for (int p = 0; p < 2; ++p) {                                              \
      int gid = t + p * 256; int m_ = gid >> 3, cg = gid & 7;                  \
      apre[p] = *(const short8_t*)(Knb + (size_t)m_ * 4096 + (ch_) * 64 + cg * 8); \
    } } while (0)

#define T_LOADB(ch_) do {                                                      \
    const float* s_ = bbase + (ch_) * 64;                                      \
    _Pragma("unroll")                                                          \
    for (int q = 0; q < 8; ++q) bpre[q] = *(const f32x4*)(s_ + q * 4);         \
    } while (0)

#define T_STORE(pb) do {                                                       \
    unsigned short* SAp = SAb[pb]; unsigned short* SBp = SBb[pb];              \
    _Pragma("unroll")                                                          \
    for (int p = 0; p < 2; ++p) {                                              \
      int gid = t + p * 256; int m_ = gid >> 3, cg = gid & 7;                  \
      *(short8_t*)(SAp + m_ * 72 + cg * 8) = apre[p];                          \
    }                                                                          \
    _Pragma("unroll")                                                          \
    for (int j = 0; j < 4; ++j) {                                              \
      short8_t v_;                                                             \
      _Pragma("unroll")                                                        \
      for (int e = 0; e < 4; ++e) {                                            \
        float f0 = bpre[j * 2][e], f1 = bpre[j * 2 + 1][e];                    \
        xs += f0 + f1;                                                         \
        v_[e] = (short)f2bf(f0); v_[4 + e] = (short)f2bf(f1);                  \
      }                                                                        \
      *(short8_t*)(SBp + row * 72 + half * 32 + j * 8) = v_;                   \
    } } while (0)

#define T_MM(pb) do {                                                          \
    const unsigned short* SAp = SAb[pb]; const unsigned short* SBp = SBb[pb];  \
    _Pragma("unroll")                                                          \
    for (int s = 0; s < 2; ++s) {                                              \
      short8_t af[4];                                                          \
      _Pragma("unroll")                                                        \
      for (int tm = 0; tm < 4; ++tm)                                           \
        af[tm] = *(const short8_t*)(SAp + (tm * 16 + l15) * 72 + s * 32 + quad * 8); \
      _Pragma("unroll")                                                        \
      for (int tcl = 0; tcl < 2; ++tcl) {                                      \
        short8_t bf_ = *(const short8_t*)(SBp + (w * 32 + tcl * 16 + l15) * 72 + s * 32 + quad * 8); \
        _Pragma("unroll")                                                      \
        for (int tm = 0; tm < 4; ++tm) acc[tm][tcl] = MFMA(af[tm], bf_, acc[tm][tcl]); \
      } } } while (0)

  // NOTE: bpre[j*2][e] ordering: v_ holds 8 consecutive n (two f32x4's)
  T_LOADA(0); T_LOADB(0);
#pragma unroll
  for (int ch = 0; ch < 8; ++ch) {
    const int pb = ch & 1;
    T_STORE(pb);
    if (ch < 7) { T_LOADA(ch + 1); T_LOADB(ch + 1); }
    __syncthreads();
    T_MM(pb);
  }

  // xsum: lanes (2k,2k+1) share row -> pair-combine, one atomic
  xs += __shfl_xor(xs, 1);
  if (half == 0) atomicAdd(xsum + b * 512 + c0 + row, xs);
  // Tpart: plain coalesced stores (each (m,c) of this block's tile exactly once)
  float* Tp = Tpart + ((size_t)(ns * 16 + b) * 64) * 512;
#pragma unroll
  for (int tm = 0; tm < 4; ++tm)
#pragma unroll
    for (int tcl = 0; tcl < 2; ++tcl)
#pragma unroll
      for (int reg = 0; reg < 4; ++reg) {
        int m = tm * 16 + quad * 4 + reg;
        int c = c0 + w * 32 + tcl * 16 + l15;
        Tp[(size_t)m * 512 + c] = acc[tm][tcl][reg];
      }
#undef T_LOADA
#undef T_LOADB
#undef T_STORE
#undef T_MM
}

// ---------------------------------------------------------------------------
// k_red: T[b][m][k] = sum_{ns<8} Tpart[ns][b][m][k]   (f32x4, 16.8MB->2.1MB)
// grid 512 blocks x 256 threads, one f32x4 per thread.
// ---------------------------------------------------------------------------
__global__ void k_red(const float* __restrict__ Tpart, float* __restrict__ T) {
  size_t idx = (size_t)blockIdx.x * 256 + threadIdx.x;   // 131072 f32x4 total
  const f32x4* p = (const f32x4*)Tpart + idx;
  f32x4 s = p[0];
#pragma unroll
  for (int ns = 1; ns < 8; ++ns) s += p[(size_t)ns * 131072];
  ((f32x4*)T)[idx] = s;
}

// ---------------------------------------------------------------------------
// k_mat: matrix[m][c] = sum_k T[m][k]*Wv[c][k] + bv[c]*Ksum[m]  -> matT[c][m] bf16
//        Vsum[c] = Wv[c,:]*xsum + 4096*bv[c]
// R3: 2m x 4c register blocking, f32x4 LDS reads (768 ds_read_b128/thread).
// grid (16 cblocks, 16 batches), 256 threads; c-range 32 per block.
// ---------------------------------------------------------------------------
__launch_bounds__(256, 2)
__global__ void k_mat(const float* __restrict__ T, const float* __restrict__ Wv,
                      const float* __restrict__ bv, const float* __restrict__ xsum,
                      const float* __restrict__ Ksum,
                      unsigned short* __restrict__ matT, float* __restrict__ Vsum) {
  __shared__ __align__(16) unsigned char smem[27136];
  float* ST = (float*)smem;             // 64 x 68
  float* SW = (float*)(smem + 17408);   // 32 x 68
  float* SV = (float*)(smem + 26112);   // 256
  const int t = threadIdx.x;
  const int cb = blockIdx.x, b = blockIdx.y;
  const int c0 = cb * 32;
  const int mp = t >> 3, cs = t & 7;    // rows {2mp,2mp+1}, cols {cs+8j}
  f32x4 acc0 = (f32x4){0.f, 0.f, 0.f, 0.f};
  f32x4 acc1 = (f32x4){0.f, 0.f, 0.f, 0.f};

  for (int kc = 0; kc < 8; ++kc) {
    __syncthreads();
#pragma unroll
    for (int p = 0; p < 4; ++p) {
      int idx = t + p * 256;
      int row = idx >> 4, f4 = idx & 15;
      *(f32x4*)(ST + row * 68 + f4 * 4) =
          *(const f32x4*)(T + ((size_t)b * 64 + row) * 512 + kc * 64 + f4 * 4);
    }
#pragma unroll
    for (int p = 0; p < 2; ++p) {
      int idx = t + p * 256;
      int row = idx >> 4, f4 = idx & 15;
      *(f32x4*)(SW + row * 68 + f4 * 4) =
          *(const f32x4*)(Wv + (size_t)(c0 + row) * 512 + kc * 64 + f4 * 4);
    }
    __syncthreads();
#pragma unroll 4
    for (int kk = 0; kk < 64; kk += 4) {
      f32x4 t0 = *(const f32x4*)(ST + (2 * mp) * 68 + kk);
      f32x4 t1 = *(const f32x4*)(ST + (2 * mp + 1) * 68 + kk);
#pragma unroll
      for (int j = 0; j < 4; ++j) {
        f32x4 wv = *(const f32x4*)(SW + (cs + j * 8) * 68 + kk);
#pragma unroll
        for (int e = 0; e < 4; ++e) {
          acc0[j] = fmaf(t0[e], wv[e], acc0[j]);
          acc1[j] = fmaf(t1[e], wv[e], acc1[j]);
        }
      }
    }
  }
  float ks0 = Ksum[b * 64 + 2 * mp];
  float ks1 = Ksum[b * 64 + 2 * mp + 1];
#pragma unroll
  for (int j = 0; j < 4; ++j) {
    int c = c0 + cs + j * 8;
    float bvc = bv[c];
    unsigned lo = f2bf(acc0[j] + bvc * ks0);
    unsigned hi = f2bf(acc1[j] + bvc * ks1);
    *(unsigned*)(matT + ((size_t)b * 512 + c) * 64 + 2 * mp) = lo | (hi << 16);
  }
  // Vsum
  {
    int cc = t >> 3, kp = t & 7;
    const float* wr = Wv + (size_t)(c0 + cc) * 512 + kp * 64;
    const float* xr = xsum + b * 512 + kp * 64;
    float s = 0.f;
    for (int i = 0; i < 64; ++i) s += wr[i] * xr[i];
    SV[cc * 8 + kp] = s;
  }
  __syncthreads();
  if (t < 32) {
    float s = 0.f;
#pragma unroll
    for (int i = 0; i < 8; ++i) s += SV[t * 8 + i];
    int c = c0 + t;
    Vsum[b * 512 + c] = s + 4096.0f * bv[c];
  }
}

// ---------------------------------------------------------------------------
// k_out: out[c][n] = gamma * tailor[n] * (Vsum[c] + sum_m matT[c][m]*Qn[m][n])
// K=64 MFMA GEMM; tailor computed in-block from staged Qn tile + Ksum.
// grid (32 ntiles, 4 ctiles, 16 batches), 256 threads; tile 128c x 128n.
// ---------------------------------------------------------------------------
__launch_bounds__(256, 2)
__global__ void k_out(const unsigned short* __restrict__ QnT,
                      const unsigned short* __restrict__ matT,
                      const float* __restrict__ Ksum, const float* __restrict__ Vsum,
                      const float* __restrict__ gamma, float* __restrict__ out) {
  __shared__ __align__(16) unsigned char smem[38144];
  unsigned short* SA = (unsigned short*)smem;             // 128 x 72 (matT tile)
  unsigned short* SB = (unsigned short*)(smem + 18432);   // 128 x 72 (QnT tile)
  float* Ksl  = (float*)(smem + 36864);                   // 64
  float* tail = (float*)(smem + 37120);                   // 128
  float* vs   = (float*)(smem + 37632);                   // 128
  const int t = threadIdx.x;
  const int lane = t & 63, w = t >> 6;
  const int l15 = lane & 15, quad = lane >> 4;
  const int nt = blockIdx.x, ct = blockIdx.y, b = blockIdx.z;
  const int n0 = nt * 128, c0 = ct * 128;

  const unsigned short* asrc = matT + ((size_t)b * 512 + c0) * 64;
  const unsigned short* bsrc = QnT + ((size_t)b * 4096 + n0) * 64;
#pragma unroll
  for (int p = 0; p < 4; ++p) {
    int idx = t + p * 256;
    int row = idx >> 3, seg = idx & 7;
    *(short8_t*)(SA + row * 72 + seg * 8) = *(const short8_t*)(asrc + row * 64 + seg * 8);
    *(short8_t*)(SB + row * 72 + seg * 8) = *(const short8_t*)(bsrc + row * 64 + seg * 8);
  }
  if (t < 64) Ksl[t] = Ksum[b * 64 + t];
  if (t >= 128) vs[t - 128] = Vsum[b * 512 + c0 + (t - 128)];
  __syncthreads();
  if (t < 128) {
    float d = 0.f;
#pragma unroll
    for (int mm = 0; mm < 64; ++mm) d += bf2f(SB[t * 72 + mm]) * Ksl[mm];
    tail[t] = 1.0f / fmaxf(4096.0f + d, 1e-6f);
  }

  f32x4 acc[2][8];
#pragma unroll
  for (int i = 0; i < 2; ++i)
#pragma unroll
    for (int j = 0; j < 8; ++j) acc[i][j] = (f32x4){0.f, 0.f, 0.f, 0.f};

#pragma unroll
  for (int s = 0; s < 2; ++s) {
    short8_t a0 = *(const short8_t*)(SA + (w * 32 + l15) * 72 + s * 32 + quad * 8);
    short8_t a1 = *(const short8_t*)(SA + (w * 32 + 16 + l15) * 72 + s * 32 + quad * 8);
#pragma unroll
    for (int tc = 0; tc < 8; ++tc) {
      short8_t bfr = *(const short8_t*)(SB + (tc * 16 + l15) * 72 + s * 32 + quad * 8);
      acc[0][tc] = MFMA(a0, bfr, acc[0][tc]);
      acc[1][tc] = MFMA(a1, bfr, acc[1][tc]);
    }
  }
  __syncthreads();
  const float g = gamma[0];
  float* ob = out + (size_t)b * 512 * 4096;
#pragma unroll
  for (int trl = 0; trl < 2; ++trl)
#pragma unroll
    for (int tc = 0; tc < 8; ++tc) {
      int n = tc * 16 + l15;
      float tl = tail[n] * g;
#pragma unroll
      for (int reg = 0; reg < 4; ++reg) {
        int cl = w * 32 + trl * 16 + quad * 4 + reg;
        float val = tl * (vs[cl] + acc[trl][tc][reg]);
        ob[(size_t)(c0 + cl) * 4096 + n0 + n] = val;
      }
    }
}

// ---------------------------------------------------------------------------
// workspace layout (bytes):
//   Tpart @ 0         : 8*16*64*512*4 = 16,777,216  (fully overwritten)
//   T     @ 16777216  : 16*64*512*4   = 2,097,152   (k_red output)
//   xsum  @ 18874368  : 16*512*4      = 32,768      (zeroed)
//   Ksum  @ 18907136  : 16*64*4       = 4,096       (zeroed)
//   Vsum  @ 18911232  : 32,768
//   Wqk   @ 18944000  : 128*512*2     = 131,072
//   matT  @ 19075072  : 16*512*64*2   = 1,048,576
//   QnT   @ 20123648  : 16*4096*64*2  = 8,388,608
//   Kn    @ 28512256  : 8,388,608                  (end 36,900,864)
// ---------------------------------------------------------------------------
extern "C" void kernel_launch(void* const* d_in, const int* in_sizes, int n_in,
                              void* d_out, int out_size, void* d_ws, size_t ws_size,
                              hipStream_t stream) {
  const float* x     = (const float*)d_in[0];
  const float* Wq    = (const float*)d_in[1];
  const float* bq    = (const float*)d_in[2];
  const float* Wk    = (const float*)d_in[3];
  const float* bk    = (const float*)d_in[4];
  const float* Wv    = (const float*)d_in[5];
  const float* bv    = (const float*)d_in[6];
  const float* gamma = (const float*)d_in[7];
  float* out = (float*)d_out;
  char* ws = (char*)d_ws;

  float* Tpart = (float*)(ws + 0);
  float* T     = (float*)(ws + 16777216);
  float* xsum  = (float*)(ws + 18874368);
  float* Ksum  = (float*)(ws + 18907136);
  float* Vsum  = (float*)(ws + 18911232);
  unsigned short* Wqk  = (unsigned short*)(ws + 18944000);
  unsigned short* matT = (unsigned short*)(ws + 19075072);
  unsigned short* QnT  = (unsigned short*)(ws + 20123648);
  unsigned short* Kn   = (unsigned short*)(ws + 28512256);

  hipMemsetAsync(ws + 18874368, 0, 36864, stream);   // xsum + Ksum only
  k_prep<<<256, 256, 0, stream>>>(Wq, Wk, Wqk);
  k_qk<<<dim3(32, 16), 256, 0, stream>>>(x, Wqk, bq, bk, QnT, Kn, Ksum);
  k_t<<<dim3(8, 4, 16), 256, 0, stream>>>(x, Kn, Tpart, xsum);
  k_red<<<512, 256, 0, stream>>>(Tpart, T);
  k_mat<<<dim3(16, 16), 256, 0, stream>>>(T, Wv, bv, xsum, Ksum, matT, Vsum);
  k_out<<<dim3(32, 4, 16), 256, 0, stream>>>(QnT, matT, Ksum, Vsum, gamma, out);
}